// Round 2
// baseline (1371.090 us; speedup 1.0000x reference)
//
#include <hip/hip_runtime.h>

// ChebNet classifier: 3x ChebConv(K=6) + 2x sparse pool + linear head.
// R1: two-stage linear head (was 20k same-line atomics = 266us, 0.85% HBM BW),
//     float4-vectorized prop/pool/neg/addmm.

#define TPB 256

static inline int gs(long long n) { return (int)((n + TPB - 1) / TPB); }

__global__ void k_deg(const int* __restrict__ row, float* __restrict__ deg, int E) {
    int e = blockIdx.x * blockDim.x + threadIdx.x;
    if (e < E) atomicAdd(&deg[row[e]], 1.0f);
}

__global__ void k_dinv(float* __restrict__ deg, int n) {
    int i = blockIdx.x * blockDim.x + threadIdx.x;
    if (i < n) {
        float d = deg[i];
        deg[i] = d > 0.f ? 1.0f / sqrtf(d) : 0.f;
    }
}

__global__ void k_w(const int* __restrict__ row, const int* __restrict__ col,
                    const float* __restrict__ dinv, float* __restrict__ w, int E) {
    int e = blockIdx.x * blockDim.x + threadIdx.x;
    if (e < E) w[e] = -dinv[row[e]] * dinv[col[e]];
}

__global__ void k_neg4(float4* __restrict__ dst, const float4* __restrict__ src, int n4) {
    int i = blockIdx.x * blockDim.x + threadIdx.x;
    if (i < n4) {
        float4 v = src[i];
        dst[i] = make_float4(-v.x, -v.y, -v.z, -v.w);
    }
}

// C == 3 (layer 0): one thread per edge, 3 scalar channels
__global__ void k_prop_c3(const int* __restrict__ row, const int* __restrict__ col,
                          const float* __restrict__ w, const float* __restrict__ src,
                          float* __restrict__ dst, int E, float scale) {
    int e = blockIdx.x * blockDim.x + threadIdx.x;
    if (e >= E) return;
    int r = row[e], c = col[e];
    float wv = scale * w[e];
    const float* s = src + (long long)c * 3;
    float* d = dst + (long long)r * 3;
    atomicAdd(d + 0, wv * s[0]);
    atomicAdd(d + 1, wv * s[1]);
    atomicAdd(d + 2, wv * s[2]);
}

// C % 4 == 0: thread per (edge, 4-channel group); float4 gather, 4 atomics
__global__ void k_prop4(const int* __restrict__ row, const int* __restrict__ col,
                        const float* __restrict__ w, const float* __restrict__ src,
                        float* __restrict__ dst, int E, int C4, int C, float scale) {
    int idx = blockIdx.x * blockDim.x + threadIdx.x;
    if (idx >= E * C4) return;
    int e = idx / C4, c4 = idx - e * C4;
    int r = row[e], c = col[e];
    float wv = scale * w[e];
    float4 s = *(const float4*)(src + (long long)c * C + c4 * 4);
    float* d = dst + (long long)r * C + c4 * 4;
    atomicAdd(d + 0, wv * s.x);
    atomicAdd(d + 1, wv * s.y);
    atomicAdd(d + 2, wv * s.z);
    atomicAdd(d + 3, wv * s.w);
}

// out[node][co4*4..+3] (+)= sum_ci tx[node][ci] * W[ci][co...]
__global__ void k_addmm4(float* __restrict__ out, const float* __restrict__ tx,
                         const float* __restrict__ W, const float* __restrict__ b,
                         int n, int Cin, int Cout, int init) {
    int Co4 = Cout >> 2;
    int idx = blockIdx.x * blockDim.x + threadIdx.x;
    if (idx >= n * Co4) return;
    int node = idx / Co4, co = (idx - node * Co4) * 4;
    const float* xr = tx + (long long)node * Cin;
    float* op = out + (long long)node * Cout + co;
    float4 acc = init ? *(const float4*)(b + co) : *(const float4*)op;
    for (int ci = 0; ci < Cin; ++ci) {
        float xv = xr[ci];
        float4 wv = *(const float4*)(W + (long long)ci * Cout + co);
        acc.x += xv * wv.x; acc.y += xv * wv.y;
        acc.z += xv * wv.z; acc.w += xv * wv.w;
    }
    *(float4*)op = acc;
}

// out[rows[i]][c4..] += vals[i] * relu(x[cols[i]][c4..])
__global__ void k_pool4(const int* __restrict__ rows, const int* __restrict__ cols,
                        const float* __restrict__ vals, const float* __restrict__ x,
                        float* __restrict__ out, int nnz, int C4, int C) {
    int idx = blockIdx.x * blockDim.x + threadIdx.x;
    if (idx >= nnz * C4) return;
    int i = idx / C4, c4 = idx - i * C4;
    float v = vals[i];
    float4 s = *(const float4*)(x + (long long)cols[i] * C + c4 * 4);
    float* d = out + (long long)rows[i] * C + c4 * 4;
    atomicAdd(d + 0, v * fmaxf(s.x, 0.f));
    atomicAdd(d + 1, v * fmaxf(s.y, 0.f));
    atomicAdd(d + 2, v * fmaxf(s.z, 0.f));
    atomicAdd(d + 3, v * fmaxf(s.w, 0.f));
}

// Stage 1: per-block partial dot products, partials[j*nblk + blockIdx.x]
__global__ void k_linear_partial(const float* __restrict__ lw, const float* __restrict__ x,
                                 float* __restrict__ partials, int len4, int len, int nblk) {
    float acc[10];
#pragma unroll
    for (int j = 0; j < 10; ++j) acc[j] = 0.f;
    const float4* x4 = (const float4*)x;
    for (int i = blockIdx.x * blockDim.x + threadIdx.x; i < len4;
         i += gridDim.x * blockDim.x) {
        float4 xv = x4[i];
#pragma unroll
        for (int j = 0; j < 10; ++j) {
            float4 wv = *(const float4*)(lw + (long long)j * len + i * 4);
            acc[j] += xv.x * wv.x + xv.y * wv.y + xv.z * wv.z + xv.w * wv.w;
        }
    }
    __shared__ float lds[4][10];
    int wid = threadIdx.x >> 6, lane = threadIdx.x & 63;
#pragma unroll
    for (int j = 0; j < 10; ++j) {
        float v = acc[j];
        for (int off = 32; off > 0; off >>= 1) v += __shfl_down(v, off, 64);
        if (lane == 0) lds[wid][j] = v;
    }
    __syncthreads();
    if (threadIdx.x < 10) {
        float s = lds[0][threadIdx.x] + lds[1][threadIdx.x] +
                  lds[2][threadIdx.x] + lds[3][threadIdx.x];
        partials[threadIdx.x * nblk + blockIdx.x] = s;
    }
}

// Stage 2: 10 waves, wave j reduces partials[j][0..nblk)
__global__ void k_linear_final(const float* __restrict__ partials,
                               const float* __restrict__ lb,
                               float* __restrict__ out, int nblk) {
    int j = threadIdx.x >> 6, lane = threadIdx.x & 63;
    float v = 0.f;
    for (int b = lane; b < nblk; b += 64) v += partials[j * nblk + b];
    for (int off = 32; off > 0; off >>= 1) v += __shfl_down(v, off, 64);
    if (lane == 0) out[j] = lb[j] + v;
}

extern "C" void kernel_launch(void* const* d_in, const int* in_sizes, int n_in,
                              void* d_out, int out_size, void* d_ws, size_t ws_size,
                              hipStream_t stream) {
    const int cN0 = 100000, cN1 = 25000, cN2 = 6250;
    const int cE0 = 600000, cE1 = 150000, cE2 = 40000;
    const int NBLK = 512;

    const float* pos = (const float*)d_in[0];
    const int*   ei0 = (const int*)d_in[1];
    const int*   ei1 = (const int*)d_in[2];
    const int*   ei2 = (const int*)d_in[3];
    const int*   d0r = (const int*)d_in[4];
    const int*   d0c = (const int*)d_in[5];
    const float* d0v = (const float*)d_in[6];
    const int*   d1r = (const int*)d_in[7];
    const int*   d1c = (const int*)d_in[8];
    const float* d1v = (const float*)d_in[9];
    const float* W0  = (const float*)d_in[10];
    const float* b0  = (const float*)d_in[11];
    const float* W1  = (const float*)d_in[12];
    const float* b1  = (const float*)d_in[13];
    const float* W2  = (const float*)d_in[14];
    const float* b2  = (const float*)d_in[15];
    const float* lw  = (const float*)d_in[16];
    const float* lb  = (const float*)d_in[17];
    float* outZ = (float*)d_out;

    // workspace layout (floats)
    float* ws      = (float*)d_ws;
    float* deg     = ws;                   // 100000
    float* wed     = deg + 100000;         // 600000
    float* txA     = wed + 600000;         // 800000
    float* txB     = txA + 800000;         // 800000
    float* txC     = txB + 800000;         // 800000
    float* bufOut  = txC + 800000;         // 3200000 (16B-aligned offset)
    float* bufPool = bufOut + 3200000;     // 800000
    float* lpart   = bufPool + 800000;     // 10*NBLK

    auto conv = [&](const float* x, const int* ei, int E, int n, int Cin, int Cout,
                    const float* W, const float* b, float* out) {
        hipMemsetAsync(deg, 0, (size_t)n * sizeof(float), stream);
        k_deg<<<gs(E), TPB, 0, stream>>>(ei, deg, E);
        k_dinv<<<gs(n), TPB, 0, stream>>>(deg, n);
        k_w<<<gs(E), TPB, 0, stream>>>(ei, ei + E, deg, wed, E);

        int C4 = Cin >> 2;
        auto prop = [&](const float* src, float* dst, float scale) {
            if (Cin == 3)
                k_prop_c3<<<gs(E), TPB, 0, stream>>>(ei, ei + E, wed, src, dst, E, scale);
            else
                k_prop4<<<gs((long long)E * C4), TPB, 0, stream>>>(
                    ei, ei + E, wed, src, dst, E, C4, Cin, scale);
        };
        auto addmm = [&](const float* tx, int k, int init) {
            k_addmm4<<<gs((long long)n * (Cout >> 2)), TPB, 0, stream>>>(
                out, tx, W + (long long)k * Cin * Cout, b, n, Cin, Cout, init);
        };

        // k = 0
        addmm(x, 0, 1);
        // k = 1: Tx1 = prop(x)
        float* bufs[3] = {txA, txB, txC};
        const float* tx0 = x;
        float* tx1 = txA;
        hipMemsetAsync(tx1, 0, (size_t)n * Cin * sizeof(float), stream);
        prop(x, tx1, 1.0f);
        addmm(tx1, 1, 0);
        // k = 2..5: Tx2 = 2*prop(Tx1) - Tx0
        int nxt = 1;
        for (int k = 2; k < 6; ++k) {
            float* tx2 = bufs[nxt];
            k_neg4<<<gs((long long)n * Cin / 4), TPB, 0, stream>>>(
                (float4*)tx2, (const float4*)tx0, n * Cin / 4);
            prop(tx1, tx2, 2.0f);
            addmm(tx2, k, 0);
            tx0 = tx1; tx1 = tx2; nxt = (nxt + 1) % 3;
        }
    };

    // layer 0: pos (N0x3) -> bufOut (N0x32)
    conv(pos, ei0, cE0, cN0, 3, 32, W0, b0, bufOut);
    hipMemsetAsync(bufPool, 0, (size_t)cN1 * 32 * sizeof(float), stream);
    k_pool4<<<gs((long long)cN0 * 8), TPB, 0, stream>>>(d0r, d0c, d0v, bufOut, bufPool, cN0, 8, 32);

    // layer 1: bufPool (N1x32) -> bufOut (N1x64)
    conv(bufPool, ei1, cE1, cN1, 32, 64, W1, b1, bufOut);
    hipMemsetAsync(bufPool, 0, (size_t)cN2 * 64 * sizeof(float), stream);
    k_pool4<<<gs((long long)cN1 * 16), TPB, 0, stream>>>(d1r, d1c, d1v, bufOut, bufPool, cN1, 16, 64);

    // layer 2: bufPool (N2x64) -> bufOut (N2x128), no relu on conv output
    conv(bufPool, ei2, cE2, cN2, 64, 128, W2, b2, bufOut);

    // linear head, two-stage (no contended atomics)
    k_linear_partial<<<NBLK, TPB, 0, stream>>>(lw, bufOut, lpart, cN2 * 128 / 4, cN2 * 128, NBLK);
    k_linear_final<<<1, 640, 0, stream>>>(lpart, lb, outZ, NBLK);
}

// Round 3
// 577.557 us; speedup vs baseline: 2.3739x; 2.3739x over previous
//
#include <hip/hip_runtime.h>

// ChebNet classifier: 3x ChebConv(K=6) + 2x sparse pool + linear head.
// R2: scatter-atomics were the bottleneck (device atomics RMW at HBM: 56MB
//     WRITE_SIZE per prop dispatch). Replaced with on-device CSR build
//     (count -> scan -> permute) + pure gather SpMV for prop and pool.
//     Recurrence 2*prop(Tx1)-Tx0 fused into the gather epilogue.

#define TPB 256

static inline int gs(long long n) { return (int)((n + TPB - 1) / TPB); }

// ---------- CSR build ----------

__global__ void k_count(const int* __restrict__ rows, int* __restrict__ cnt, int E) {
    int e = blockIdx.x * blockDim.x + threadIdx.x;
    if (e < E) atomicAdd(&cnt[rows[e]], 1);
}

// per-block exclusive scan; block totals to bsum
__global__ void k_scan1(const int* __restrict__ cnt, int* __restrict__ excl,
                        int* __restrict__ bsum, int n) {
    int gid = blockIdx.x * 256 + threadIdx.x;
    int v = (gid < n) ? cnt[gid] : 0;
    int lane = threadIdx.x & 63, wid = threadIdx.x >> 6;
    int s = v;
#pragma unroll
    for (int off = 1; off < 64; off <<= 1) {
        int t = __shfl_up(s, off, 64);
        if (lane >= off) s += t;
    }
    __shared__ int wsum[4];
    if (lane == 63) wsum[wid] = s;
    __syncthreads();
    int add = 0;
    for (int w = 0; w < wid; ++w) add += wsum[w];
    if (gid < n) excl[gid] = add + s - v;
    if (threadIdx.x == 255) bsum[blockIdx.x] = add + s;
}

// single-wave scan of block sums (nb <= ~400)
__global__ void k_scan2(int* __restrict__ bsum, int nb) {
    int lane = threadIdx.x;  // blockDim = 64
    int carry = 0;
    for (int base = 0; base < nb; base += 64) {
        int i = base + lane;
        int v = (i < nb) ? bsum[i] : 0;
        int s = v;
#pragma unroll
        for (int off = 1; off < 64; off <<= 1) {
            int t = __shfl_up(s, off, 64);
            if (lane >= off) s += t;
        }
        if (i < nb) bsum[i] = carry + s - v;
        carry += __shfl(s, 63, 64);
    }
}

__global__ void k_scan3(int* __restrict__ rowptr, const int* __restrict__ bsum,
                        int n, int E) {
    int gid = blockIdx.x * 256 + threadIdx.x;
    if (gid < n) rowptr[gid] += bsum[blockIdx.x];
    if (gid == 0) rowptr[n] = E;
}

__global__ void k_scatter(const int* __restrict__ rows, const int* __restrict__ cols,
                          const float* __restrict__ vals, const int* __restrict__ rowptr,
                          int* __restrict__ cursor, int* __restrict__ colsp,
                          float* __restrict__ valsp, int E) {
    int e = blockIdx.x * blockDim.x + threadIdx.x;
    if (e >= E) return;
    int r = rows[e];
    int pos = rowptr[r] + atomicAdd(&cursor[r], 1);
    colsp[pos] = cols[e];
    if (valsp) valsp[pos] = vals[e];
}

__global__ void k_dinv_i(const int* __restrict__ cnt, float* __restrict__ dinv, int n) {
    int i = blockIdx.x * blockDim.x + threadIdx.x;
    if (i < n) {
        int d = cnt[i];
        dinv[i] = d > 0 ? 1.0f / sqrtf((float)d) : 0.f;
    }
}

// ---------- gather SpMV (Cheb prop) ----------
// sum = prop(src)[r] = -dinv[r] * sum_j dinv[col_j] * src[col_j]
// mode 0: dst = sum ; mode 1: dst = 2*sum - prev   (prev may alias dst)

__global__ void k_sprop3(const int* __restrict__ rowptr, const int* __restrict__ colsp,
                         const float* __restrict__ dinv, const float* __restrict__ src,
                         const float* __restrict__ prev, float* __restrict__ dst,
                         int n, int mode) {
    int r = blockIdx.x * blockDim.x + threadIdx.x;
    if (r >= n) return;
    int s0 = rowptr[r], s1 = rowptr[r + 1];
    float a0 = 0.f, a1 = 0.f, a2 = 0.f;
    for (int j = s0; j < s1; ++j) {
        int c = colsp[j];
        float w = dinv[c];
        const float* sp = src + (long long)c * 3;
        a0 += w * sp[0]; a1 += w * sp[1]; a2 += w * sp[2];
    }
    float m = -dinv[r];
    a0 *= m; a1 *= m; a2 *= m;
    long long o = (long long)r * 3;
    if (mode) {
        dst[o]     = 2.f * a0 - prev[o];
        dst[o + 1] = 2.f * a1 - prev[o + 1];
        dst[o + 2] = 2.f * a2 - prev[o + 2];
    } else {
        dst[o] = a0; dst[o + 1] = a1; dst[o + 2] = a2;
    }
}

__global__ void k_sprop4(const int* __restrict__ rowptr, const int* __restrict__ colsp,
                         const float* __restrict__ dinv, const float* __restrict__ src,
                         const float* __restrict__ prev, float* __restrict__ dst,
                         int n, int C4, int C, int mode) {
    int idx = blockIdx.x * blockDim.x + threadIdx.x;
    if (idx >= n * C4) return;
    int r = idx / C4, c4 = (idx - r * C4) * 4;
    int s0 = rowptr[r], s1 = rowptr[r + 1];
    float4 acc = make_float4(0.f, 0.f, 0.f, 0.f);
    for (int j = s0; j < s1; ++j) {
        int c = colsp[j];
        float w = dinv[c];
        float4 s = *(const float4*)(src + (long long)c * C + c4);
        acc.x += w * s.x; acc.y += w * s.y; acc.z += w * s.z; acc.w += w * s.w;
    }
    float m = -dinv[r];
    long long o = (long long)r * C + c4;
    float4 out;
    if (mode) {
        float4 p = *(const float4*)(prev + o);
        out.x = 2.f * m * acc.x - p.x; out.y = 2.f * m * acc.y - p.y;
        out.z = 2.f * m * acc.z - p.z; out.w = 2.f * m * acc.w - p.w;
    } else {
        out.x = m * acc.x; out.y = m * acc.y; out.z = m * acc.z; out.w = m * acc.w;
    }
    *(float4*)(dst + o) = out;
}

// ---------- gather pool: out[r] = sum_j vals_j * relu(x[col_j]) ----------

__global__ void k_spool4(const int* __restrict__ rowptr, const int* __restrict__ colsp,
                         const float* __restrict__ valsp, const float* __restrict__ x,
                         float* __restrict__ out, int n, int C4, int C) {
    int idx = blockIdx.x * blockDim.x + threadIdx.x;
    if (idx >= n * C4) return;
    int r = idx / C4, c4 = (idx - r * C4) * 4;
    int s0 = rowptr[r], s1 = rowptr[r + 1];
    float4 acc = make_float4(0.f, 0.f, 0.f, 0.f);
    for (int j = s0; j < s1; ++j) {
        int c = colsp[j];
        float v = valsp[j];
        float4 s = *(const float4*)(x + (long long)c * C + c4);
        acc.x += v * fmaxf(s.x, 0.f); acc.y += v * fmaxf(s.y, 0.f);
        acc.z += v * fmaxf(s.z, 0.f); acc.w += v * fmaxf(s.w, 0.f);
    }
    *(float4*)(out + (long long)r * C + c4) = acc;
}

// ---------- dense: out[node][co..co+3] (+)= sum_ci tx[node][ci]*W[ci][co..] ----------

__global__ void k_addmm4(float* __restrict__ out, const float* __restrict__ tx,
                         const float* __restrict__ W, const float* __restrict__ b,
                         int n, int Cin, int Cout, int init) {
    int Co4 = Cout >> 2;
    int idx = blockIdx.x * blockDim.x + threadIdx.x;
    if (idx >= n * Co4) return;
    int node = idx / Co4, co = (idx - node * Co4) * 4;
    const float* xr = tx + (long long)node * Cin;
    float* op = out + (long long)node * Cout + co;
    float4 acc = init ? *(const float4*)(b + co) : *(const float4*)op;
    for (int ci = 0; ci < Cin; ++ci) {
        float xv = xr[ci];
        float4 wv = *(const float4*)(W + (long long)ci * Cout + co);
        acc.x += xv * wv.x; acc.y += xv * wv.y;
        acc.z += xv * wv.z; acc.w += xv * wv.w;
    }
    *(float4*)op = acc;
}

// ---------- linear head, two-stage ----------

__global__ void k_linear_partial(const float* __restrict__ lw, const float* __restrict__ x,
                                 float* __restrict__ partials, int len4, int len, int nblk) {
    float acc[10];
#pragma unroll
    for (int j = 0; j < 10; ++j) acc[j] = 0.f;
    const float4* x4 = (const float4*)x;
    for (int i = blockIdx.x * blockDim.x + threadIdx.x; i < len4;
         i += gridDim.x * blockDim.x) {
        float4 xv = x4[i];
#pragma unroll
        for (int j = 0; j < 10; ++j) {
            float4 wv = *(const float4*)(lw + (long long)j * len + i * 4);
            acc[j] += xv.x * wv.x + xv.y * wv.y + xv.z * wv.z + xv.w * wv.w;
        }
    }
    __shared__ float lds[4][10];
    int wid = threadIdx.x >> 6, lane = threadIdx.x & 63;
#pragma unroll
    for (int j = 0; j < 10; ++j) {
        float v = acc[j];
        for (int off = 32; off > 0; off >>= 1) v += __shfl_down(v, off, 64);
        if (lane == 0) lds[wid][j] = v;
    }
    __syncthreads();
    if (threadIdx.x < 10) {
        float s = lds[0][threadIdx.x] + lds[1][threadIdx.x] +
                  lds[2][threadIdx.x] + lds[3][threadIdx.x];
        partials[threadIdx.x * nblk + blockIdx.x] = s;
    }
}

__global__ void k_linear_final(const float* __restrict__ partials,
                               const float* __restrict__ lb,
                               float* __restrict__ out, int nblk) {
    int j = threadIdx.x >> 6, lane = threadIdx.x & 63;
    float v = 0.f;
    for (int b = lane; b < nblk; b += 64) v += partials[j * nblk + b];
    for (int off = 32; off > 0; off >>= 1) v += __shfl_down(v, off, 64);
    if (lane == 0) out[j] = lb[j] + v;
}

extern "C" void kernel_launch(void* const* d_in, const int* in_sizes, int n_in,
                              void* d_out, int out_size, void* d_ws, size_t ws_size,
                              hipStream_t stream) {
    const int cN0 = 100000, cN1 = 25000, cN2 = 6250;
    const int cE0 = 600000, cE1 = 150000, cE2 = 40000;
    const int NBLK = 512;

    const float* pos = (const float*)d_in[0];
    const int*   ei0 = (const int*)d_in[1];
    const int*   ei1 = (const int*)d_in[2];
    const int*   ei2 = (const int*)d_in[3];
    const int*   d0r = (const int*)d_in[4];
    const int*   d0c = (const int*)d_in[5];
    const float* d0v = (const float*)d_in[6];
    const int*   d1r = (const int*)d_in[7];
    const int*   d1c = (const int*)d_in[8];
    const float* d1v = (const float*)d_in[9];
    const float* W0  = (const float*)d_in[10];
    const float* b0  = (const float*)d_in[11];
    const float* W1  = (const float*)d_in[12];
    const float* b1  = (const float*)d_in[13];
    const float* W2  = (const float*)d_in[14];
    const float* b2  = (const float*)d_in[15];
    const float* lw  = (const float*)d_in[16];
    const float* lb  = (const float*)d_in[17];
    float* outZ = (float*)d_out;

    // workspace layout (4B units)
    float* ws     = (float*)d_ws;
    float* dinv   = ws;                      // 100000 f
    int*   ideg   = (int*)(dinv + 100000);   // 100000 i
    int*   cursor = ideg + 100000;           // 100000 i
    int*   rowptr = cursor + 100000;         // 100008 i (n+1 max 100001)
    int*   bsum   = rowptr + 100008;         // 512 i
    int*   colsp  = bsum + 512;              // 600000 i
    float* valsp  = (float*)(colsp + 600000);// 100000 f
    float* txA    = valsp + 100000;          // 800000 f
    float* txB    = txA + 800000;            // 800000 f
    float* bufOut = txB + 800000;            // 3200000 f
    float* bufPool= bufOut + 3200000;        // 800000 f
    float* lpart  = bufPool + 800000;        // 5120 f

    auto build_csr = [&](const int* rows, const int* cols, const float* vals,
                         int n, int E, int want_dinv) {
        hipMemsetAsync(ideg, 0, (size_t)n * 4, stream);
        k_count<<<gs(E), TPB, 0, stream>>>(rows, ideg, E);
        int nb = (n + 255) / 256;
        k_scan1<<<nb, 256, 0, stream>>>(ideg, rowptr, bsum, n);
        k_scan2<<<1, 64, 0, stream>>>(bsum, nb);
        k_scan3<<<nb, 256, 0, stream>>>(rowptr, bsum, n, E);
        if (want_dinv) k_dinv_i<<<gs(n), TPB, 0, stream>>>(ideg, dinv, n);
        hipMemsetAsync(cursor, 0, (size_t)n * 4, stream);
        k_scatter<<<gs(E), TPB, 0, stream>>>(rows, cols, vals, rowptr, cursor,
                                             colsp, vals ? valsp : nullptr, E);
    };

    auto conv = [&](const float* x, const int* ei, int E, int n, int Cin, int Cout,
                    const float* W, const float* b, float* out) {
        build_csr(ei, ei + E, nullptr, n, E, 1);

        auto sprop = [&](const float* src, const float* prev, float* dst, int mode) {
            if (Cin == 3)
                k_sprop3<<<gs(n), TPB, 0, stream>>>(rowptr, colsp, dinv, src, prev, dst, n, mode);
            else
                k_sprop4<<<gs((long long)n * (Cin >> 2)), TPB, 0, stream>>>(
                    rowptr, colsp, dinv, src, prev, dst, n, Cin >> 2, Cin, mode);
        };
        auto addmm = [&](const float* tx, int k, int init) {
            k_addmm4<<<gs((long long)n * (Cout >> 2)), TPB, 0, stream>>>(
                out, tx, W + (long long)k * Cin * Cout, b, n, Cin, Cout, init);
        };

        addmm(x, 0, 1);
        sprop(x, nullptr, txA, 0);  addmm(txA, 1, 0);   // Tx1
        sprop(txA, x, txB, 1);      addmm(txB, 2, 0);   // Tx2 = 2 prop(Tx1) - x
        sprop(txB, txA, txA, 1);    addmm(txA, 3, 0);   // in-place prev==dst is safe
        sprop(txA, txB, txB, 1);    addmm(txB, 4, 0);
        sprop(txB, txA, txA, 1);    addmm(txA, 5, 0);
    };

    auto pool = [&](const int* rows, const int* cols, const float* vals, int nnz,
                    int n_out, const float* x, float* out, int C) {
        build_csr(rows, cols, vals, n_out, nnz, 0);
        k_spool4<<<gs((long long)n_out * (C >> 2)), TPB, 0, stream>>>(
            rowptr, colsp, valsp, x, out, n_out, C >> 2, C);
    };

    // layer 0: pos (N0x3) -> bufOut (N0x32); pool -> bufPool (N1x32)
    conv(pos, ei0, cE0, cN0, 3, 32, W0, b0, bufOut);
    pool(d0r, d0c, d0v, cN0, cN1, bufOut, bufPool, 32);

    // layer 1: bufPool (N1x32) -> bufOut (N1x64); pool -> bufPool (N2x64)
    conv(bufPool, ei1, cE1, cN1, 32, 64, W1, b1, bufOut);
    pool(d1r, d1c, d1v, cN1, cN2, bufOut, bufPool, 64);

    // layer 2: bufPool (N2x64) -> bufOut (N2x128), no relu
    conv(bufPool, ei2, cE2, cN2, 64, 128, W2, b2, bufOut);

    // linear head
    k_linear_partial<<<NBLK, TPB, 0, stream>>>(lw, bufOut, lpart, cN2 * 128 / 4, cN2 * 128, NBLK);
    k_linear_final<<<1, 640, 0, stream>>>(lpart, lb, outZ, NBLK);
}

// Round 4
// 450.085 us; speedup vs baseline: 3.0463x; 1.2832x over previous
//
#include <hip/hip_runtime.h>

// ChebNet classifier: 3x ChebConv(K=6) + 2x sparse pool + linear head.
// R3: (a) single batched CSR build for all 5 sparse structures (one global
//     concatenated rowptr/colsp -- prefix sums give per-structure colsp bases
//     for free); (b) Tx1..Tx5 materialized, then ONE fused out-GEMM per conv
//     (out = b + sum_k Tx_k W[k]) replacing 6 RMW addmm passes.
//     Dispatches: 75 -> 29.

#define TPB 256

static inline int gs(long long n) { return (int)((n + TPB - 1) / TPB); }

struct Desc5 {
    const int* rows[5];
    const int* cols[5];
    const float* vals[5];
    int eoff[6];   // edge offsets into concatenated edge space
    int doff[5];   // row offsets into concatenated row space
};

struct TxPtrs { const float* p[6]; };

// ---------- batched CSR build ----------

__global__ void k_count_all(Desc5 d, int* __restrict__ cnt, int Etot) {
    int e = blockIdx.x * blockDim.x + threadIdx.x;
    if (e >= Etot) return;
    int s = 0;
    while (e >= d.eoff[s + 1]) ++s;
    int le = e - d.eoff[s];
    atomicAdd(&cnt[d.doff[s] + d.rows[s][le]], 1);
}

// per-block exclusive scan; block totals to bsum
__global__ void k_scan1(const int* __restrict__ cnt, int* __restrict__ excl,
                        int* __restrict__ bsum, int n) {
    int gid = blockIdx.x * 256 + threadIdx.x;
    int v = (gid < n) ? cnt[gid] : 0;
    int lane = threadIdx.x & 63, wid = threadIdx.x >> 6;
    int s = v;
#pragma unroll
    for (int off = 1; off < 64; off <<= 1) {
        int t = __shfl_up(s, off, 64);
        if (lane >= off) s += t;
    }
    __shared__ int wsum[4];
    if (lane == 63) wsum[wid] = s;
    __syncthreads();
    int add = 0;
    for (int w = 0; w < wid; ++w) add += wsum[w];
    if (gid < n) excl[gid] = add + s - v;
    if (threadIdx.x == 255) bsum[blockIdx.x] = add + s;
}

__global__ void k_scan2(int* __restrict__ bsum, int nb) {
    int lane = threadIdx.x;  // blockDim = 64
    int carry = 0;
    for (int base = 0; base < nb; base += 64) {
        int i = base + lane;
        int v = (i < nb) ? bsum[i] : 0;
        int s = v;
#pragma unroll
        for (int off = 1; off < 64; off <<= 1) {
            int t = __shfl_up(s, off, 64);
            if (lane >= off) s += t;
        }
        if (i < nb) bsum[i] = carry + s - v;
        carry += __shfl(s, 63, 64);
    }
}

__global__ void k_scan3(int* __restrict__ rowptr, const int* __restrict__ bsum,
                        int n, int E) {
    int gid = blockIdx.x * 256 + threadIdx.x;
    if (gid < n) rowptr[gid] += bsum[blockIdx.x];
    if (gid == 0) rowptr[n] = E;
}

__global__ void k_dinv_i(const int* __restrict__ cnt, float* __restrict__ dinv, int n) {
    int i = blockIdx.x * blockDim.x + threadIdx.x;
    if (i < n) {
        int d = cnt[i];
        dinv[i] = d > 0 ? 1.0f / sqrtf((float)d) : 0.f;
    }
}

__global__ void k_scatter_all(Desc5 d, const int* __restrict__ rowptr,
                              int* __restrict__ cursor, int* __restrict__ colsp,
                              float* __restrict__ valsp, int Etot) {
    int e = blockIdx.x * blockDim.x + threadIdx.x;
    if (e >= Etot) return;
    int s = 0;
    while (e >= d.eoff[s + 1]) ++s;
    int le = e - d.eoff[s];
    int gr = d.doff[s] + d.rows[s][le];
    int pos = rowptr[gr] + atomicAdd(&cursor[gr], 1);
    colsp[pos] = d.cols[s][le];
    if (d.vals[s]) valsp[pos] = d.vals[s][le];
}

// ---------- gather SpMV (Cheb prop) ----------
// acc = sum_j dinv[col_j]*src[col_j]; prop = -dinv[r]*acc
// mode 0: dst = prop ; mode 1: dst = 2*prop - prev

__global__ void k_sprop3(const int* __restrict__ rowptr, const int* __restrict__ colsp,
                         const float* __restrict__ dinv, const float* __restrict__ src,
                         const float* __restrict__ prev, float* __restrict__ dst,
                         int n, int mode) {
    int r = blockIdx.x * blockDim.x + threadIdx.x;
    if (r >= n) return;
    int s0 = rowptr[r], s1 = rowptr[r + 1];
    float a0 = 0.f, a1 = 0.f, a2 = 0.f;
    for (int j = s0; j < s1; ++j) {
        int c = colsp[j];
        float w = dinv[c];
        const float* sp = src + (long long)c * 3;
        a0 += w * sp[0]; a1 += w * sp[1]; a2 += w * sp[2];
    }
    float m = -dinv[r];
    long long o = (long long)r * 3;
    if (mode) {
        dst[o]     = 2.f * m * a0 - prev[o];
        dst[o + 1] = 2.f * m * a1 - prev[o + 1];
        dst[o + 2] = 2.f * m * a2 - prev[o + 2];
    } else {
        dst[o] = m * a0; dst[o + 1] = m * a1; dst[o + 2] = m * a2;
    }
}

__global__ void k_sprop4(const int* __restrict__ rowptr, const int* __restrict__ colsp,
                         const float* __restrict__ dinv, const float* __restrict__ src,
                         const float* __restrict__ prev, float* __restrict__ dst,
                         int n, int C4, int C, int mode) {
    int idx = blockIdx.x * blockDim.x + threadIdx.x;
    if (idx >= n * C4) return;
    int r = idx / C4, c4 = (idx - r * C4) * 4;
    int s0 = rowptr[r], s1 = rowptr[r + 1];
    float4 acc = make_float4(0.f, 0.f, 0.f, 0.f);
    for (int j = s0; j < s1; ++j) {
        int c = colsp[j];
        float w = dinv[c];
        float4 s = *(const float4*)(src + (long long)c * C + c4);
        acc.x += w * s.x; acc.y += w * s.y; acc.z += w * s.z; acc.w += w * s.w;
    }
    float m = -dinv[r];
    long long o = (long long)r * C + c4;
    float4 out;
    if (mode) {
        float4 p = *(const float4*)(prev + o);
        out.x = 2.f * m * acc.x - p.x; out.y = 2.f * m * acc.y - p.y;
        out.z = 2.f * m * acc.z - p.z; out.w = 2.f * m * acc.w - p.w;
    } else {
        out.x = m * acc.x; out.y = m * acc.y; out.z = m * acc.z; out.w = m * acc.w;
    }
    *(float4*)(dst + o) = out;
}

// ---------- gather pool: out[r] = sum_j vals_j * relu(x[col_j]) ----------

__global__ void k_spool4(const int* __restrict__ rowptr, const int* __restrict__ colsp,
                         const float* __restrict__ valsp, const float* __restrict__ x,
                         float* __restrict__ out, int n, int C4, int C) {
    int idx = blockIdx.x * blockDim.x + threadIdx.x;
    if (idx >= n * C4) return;
    int r = idx / C4, c4 = (idx - r * C4) * 4;
    int s0 = rowptr[r], s1 = rowptr[r + 1];
    float4 acc = make_float4(0.f, 0.f, 0.f, 0.f);
    for (int j = s0; j < s1; ++j) {
        int c = colsp[j];
        float v = valsp[j];
        float4 s = *(const float4*)(x + (long long)c * C + c4);
        acc.x += v * fmaxf(s.x, 0.f); acc.y += v * fmaxf(s.y, 0.f);
        acc.z += v * fmaxf(s.z, 0.f); acc.w += v * fmaxf(s.w, 0.f);
    }
    *(float4*)(out + (long long)r * C + c4) = acc;
}

// ---------- fused output GEMM: out = b + sum_k Tx_k @ W[k], pure write ----------

__global__ void k_outgemm(float* __restrict__ out, TxPtrs txs,
                          const float* __restrict__ W, const float* __restrict__ b,
                          int n, int Cin, int Cout) {
    int Co4 = Cout >> 2;
    int idx = blockIdx.x * blockDim.x + threadIdx.x;
    if (idx >= n * Co4) return;
    int node = idx / Co4, co = (idx - node * Co4) * 4;
    float4 acc = *(const float4*)(b + co);
#pragma unroll
    for (int k = 0; k < 6; ++k) {
        const float* xr = txs.p[k] + (long long)node * Cin;
        const float* Wk = W + (long long)k * Cin * Cout + co;
        for (int ci = 0; ci < Cin; ++ci) {
            float xv = xr[ci];
            float4 wv = *(const float4*)(Wk + (long long)ci * Cout);
            acc.x += xv * wv.x; acc.y += xv * wv.y;
            acc.z += xv * wv.z; acc.w += xv * wv.w;
        }
    }
    *(float4*)(out + (long long)node * Cout + co) = acc;
}

// ---------- linear head, two-stage ----------

__global__ void k_linear_partial(const float* __restrict__ lw, const float* __restrict__ x,
                                 float* __restrict__ partials, int len4, int len, int nblk) {
    float acc[10];
#pragma unroll
    for (int j = 0; j < 10; ++j) acc[j] = 0.f;
    const float4* x4 = (const float4*)x;
    for (int i = blockIdx.x * blockDim.x + threadIdx.x; i < len4;
         i += gridDim.x * blockDim.x) {
        float4 xv = x4[i];
#pragma unroll
        for (int j = 0; j < 10; ++j) {
            float4 wv = *(const float4*)(lw + (long long)j * len + i * 4);
            acc[j] += xv.x * wv.x + xv.y * wv.y + xv.z * wv.z + xv.w * wv.w;
        }
    }
    __shared__ float lds[4][10];
    int wid = threadIdx.x >> 6, lane = threadIdx.x & 63;
#pragma unroll
    for (int j = 0; j < 10; ++j) {
        float v = acc[j];
        for (int off = 32; off > 0; off >>= 1) v += __shfl_down(v, off, 64);
        if (lane == 0) lds[wid][j] = v;
    }
    __syncthreads();
    if (threadIdx.x < 10) {
        float s = lds[0][threadIdx.x] + lds[1][threadIdx.x] +
                  lds[2][threadIdx.x] + lds[3][threadIdx.x];
        partials[threadIdx.x * nblk + blockIdx.x] = s;
    }
}

__global__ void k_linear_final(const float* __restrict__ partials,
                               const float* __restrict__ lb,
                               float* __restrict__ out, int nblk) {
    int j = threadIdx.x >> 6, lane = threadIdx.x & 63;
    float v = 0.f;
    for (int b = lane; b < nblk; b += 64) v += partials[j * nblk + b];
    for (int off = 32; off > 0; off >>= 1) v += __shfl_down(v, off, 64);
    if (lane == 0) out[j] = lb[j] + v;
}

extern "C" void kernel_launch(void* const* d_in, const int* in_sizes, int n_in,
                              void* d_out, int out_size, void* d_ws, size_t ws_size,
                              hipStream_t stream) {
    const int cN0 = 100000, cN1 = 25000, cN2 = 6250;
    const int cE0 = 600000, cE1 = 150000, cE2 = 40000;
    const int NBLK = 512;

    const float* pos = (const float*)d_in[0];
    const int*   ei0 = (const int*)d_in[1];
    const int*   ei1 = (const int*)d_in[2];
    const int*   ei2 = (const int*)d_in[3];
    const int*   d0r = (const int*)d_in[4];
    const int*   d0c = (const int*)d_in[5];
    const float* d0v = (const float*)d_in[6];
    const int*   d1r = (const int*)d_in[7];
    const int*   d1c = (const int*)d_in[8];
    const float* d1v = (const float*)d_in[9];
    const float* W0  = (const float*)d_in[10];
    const float* b0  = (const float*)d_in[11];
    const float* W1  = (const float*)d_in[12];
    const float* b1  = (const float*)d_in[13];
    const float* W2  = (const float*)d_in[14];
    const float* b2  = (const float*)d_in[15];
    const float* lw  = (const float*)d_in[16];
    const float* lb  = (const float*)d_in[17];
    float* outZ = (float*)d_out;

    // concatenated row space: g0 g1 g2 p0 p1
    const int ntot = cN0 + cN1 + cN2 + cN1 + cN2;          // 162500
    const int Etot = cE0 + cE1 + cE2 + cN0 + cN1;          // 915000
    const int doff0 = 0, doff1 = cN0, doff2 = cN0 + cN1,
              doffp0 = doff2 + cN2, doffp1 = doffp0 + cN1;

    // workspace layout (4B units)
    int*   iws    = (int*)d_ws;
    int*   ideg   = iws;                     // 162500
    int*   cursor = ideg + 162500;           // 162500 (adjacent: one memset)
    int*   rowptr = cursor + 162500;         // 162501
    int*   bsum   = rowptr + 162504;         // 704
    float* dinv   = (float*)(bsum + 704);    // 131250
    int*   colsp  = (int*)(dinv + 131250);   // 915000
    float* valsp  = (float*)(colsp + 915000);// 915000
    float* txbuf  = valsp + 915002;          // 5 x 800000 (16B aligned)
    float* bufOut = txbuf + 5 * 800000;      // 3200000
    float* bufPool= bufOut + 3200000;        // 800000
    float* lpart  = bufPool + 800000;        // 5120

    // ---- batched CSR build (7 dispatches) ----
    Desc5 d;
    d.rows[0] = ei0;        d.cols[0] = ei0 + cE0; d.vals[0] = nullptr;
    d.rows[1] = ei1;        d.cols[1] = ei1 + cE1; d.vals[1] = nullptr;
    d.rows[2] = ei2;        d.cols[2] = ei2 + cE2; d.vals[2] = nullptr;
    d.rows[3] = d0r;        d.cols[3] = d0c;       d.vals[3] = d0v;
    d.rows[4] = d1r;        d.cols[4] = d1c;       d.vals[4] = d1v;
    d.eoff[0] = 0;
    d.eoff[1] = cE0;
    d.eoff[2] = cE0 + cE1;
    d.eoff[3] = cE0 + cE1 + cE2;
    d.eoff[4] = cE0 + cE1 + cE2 + cN0;
    d.eoff[5] = Etot;
    d.doff[0] = doff0; d.doff[1] = doff1; d.doff[2] = doff2;
    d.doff[3] = doffp0; d.doff[4] = doffp1;

    hipMemsetAsync(ideg, 0, (size_t)(162500 + 162500) * 4, stream);
    k_count_all<<<gs(Etot), TPB, 0, stream>>>(d, ideg, Etot);
    int nb = (ntot + 255) / 256;
    k_scan1<<<nb, 256, 0, stream>>>(ideg, rowptr, bsum, ntot);
    k_scan2<<<1, 64, 0, stream>>>(bsum, nb);
    k_scan3<<<nb, 256, 0, stream>>>(rowptr, bsum, ntot, Etot);
    k_dinv_i<<<gs(cN0 + cN1 + cN2), TPB, 0, stream>>>(ideg, dinv, cN0 + cN1 + cN2);
    k_scatter_all<<<gs(Etot), TPB, 0, stream>>>(d, rowptr, cursor, colsp, valsp, Etot);

    auto conv = [&](const float* x, int doffs, int n, int Cin, int Cout,
                    const float* W, const float* b, float* out) {
        const int* rp = rowptr + doffs;
        const float* dv = dinv + doffs;
        auto sprop = [&](const float* src, const float* prev, float* dst, int mode) {
            if (Cin == 3)
                k_sprop3<<<gs(n), TPB, 0, stream>>>(rp, colsp, dv, src, prev, dst, n, mode);
            else
                k_sprop4<<<gs((long long)n * (Cin >> 2)), TPB, 0, stream>>>(
                    rp, colsp, dv, src, prev, dst, n, Cin >> 2, Cin, mode);
        };
        TxPtrs txs;
        txs.p[0] = x;
        for (int i = 1; i < 6; ++i) txs.p[i] = txbuf + (long long)(i - 1) * 800000;
        sprop(txs.p[0], nullptr, (float*)txs.p[1], 0);
        for (int k = 2; k < 6; ++k)
            sprop(txs.p[k - 1], txs.p[k - 2], (float*)txs.p[k], 1);
        k_outgemm<<<gs((long long)n * (Cout >> 2)), TPB, 0, stream>>>(
            out, txs, W, b, n, Cin, Cout);
    };

    // layer 0: pos (N0x3) -> bufOut (N0x32); pool -> bufPool (N1x32)
    conv(pos, doff0, cN0, 3, 32, W0, b0, bufOut);
    k_spool4<<<gs((long long)cN1 * 8), TPB, 0, stream>>>(
        rowptr + doffp0, colsp, valsp, bufOut, bufPool, cN1, 8, 32);

    // layer 1: bufPool (N1x32) -> bufOut (N1x64); pool -> bufPool (N2x64)
    conv(bufPool, doff1, cN1, 32, 64, W1, b1, bufOut);
    k_spool4<<<gs((long long)cN2 * 16), TPB, 0, stream>>>(
        rowptr + doffp1, colsp, valsp, bufOut, bufPool, cN2, 16, 64);

    // layer 2: bufPool (N2x64) -> bufOut (N2x128), no relu
    conv(bufPool, doff2, cN2, 64, 128, W2, b2, bufOut);

    // linear head
    k_linear_partial<<<NBLK, TPB, 0, stream>>>(lw, bufOut, lpart, cN2 * 128 / 4, cN2 * 128, NBLK);
    k_linear_final<<<1, 640, 0, stream>>>(lpart, lb, outZ, NBLK);
}

// Round 5
// 367.732 us; speedup vs baseline: 3.7285x; 1.2239x over previous
//
#include <hip/hip_runtime.h>

// ChebNet classifier: 3x ChebConv(K=6) + 2x sparse pool + linear head.
// R4: layer-2 k_outgemm was 130us at 5% VALUBusy -- runtime-trip-count inner
//     loop exposed ~384 serial load latencies/thread with only 12 waves/CU.
//     Templated outgemm on (CIN,COUT) w/ full unroll + register x-row (ILP),
//     2x-unrolled edge loops in sprop/spool (independent load chains).

#define TPB 256

static inline int gs(long long n) { return (int)((n + TPB - 1) / TPB); }

struct Desc5 {
    const int* rows[5];
    const int* cols[5];
    const float* vals[5];
    int eoff[6];
    int doff[5];
};

struct TxPtrs { const float* p[6]; };

// ---------- batched CSR build ----------

__global__ void k_count_all(Desc5 d, int* __restrict__ cnt, int Etot) {
    int e = blockIdx.x * blockDim.x + threadIdx.x;
    if (e >= Etot) return;
    int s = 0;
    while (e >= d.eoff[s + 1]) ++s;
    int le = e - d.eoff[s];
    atomicAdd(&cnt[d.doff[s] + d.rows[s][le]], 1);
}

__global__ void k_scan1(const int* __restrict__ cnt, int* __restrict__ excl,
                        int* __restrict__ bsum, int n) {
    int gid = blockIdx.x * 256 + threadIdx.x;
    int v = (gid < n) ? cnt[gid] : 0;
    int lane = threadIdx.x & 63, wid = threadIdx.x >> 6;
    int s = v;
#pragma unroll
    for (int off = 1; off < 64; off <<= 1) {
        int t = __shfl_up(s, off, 64);
        if (lane >= off) s += t;
    }
    __shared__ int wsum[4];
    if (lane == 63) wsum[wid] = s;
    __syncthreads();
    int add = 0;
    for (int w = 0; w < wid; ++w) add += wsum[w];
    if (gid < n) excl[gid] = add + s - v;
    if (threadIdx.x == 255) bsum[blockIdx.x] = add + s;
}

__global__ void k_scan2(int* __restrict__ bsum, int nb) {
    int lane = threadIdx.x;  // blockDim = 64
    int carry = 0;
    for (int base = 0; base < nb; base += 64) {
        int i = base + lane;
        int v = (i < nb) ? bsum[i] : 0;
        int s = v;
#pragma unroll
        for (int off = 1; off < 64; off <<= 1) {
            int t = __shfl_up(s, off, 64);
            if (lane >= off) s += t;
        }
        if (i < nb) bsum[i] = carry + s - v;
        carry += __shfl(s, 63, 64);
    }
}

__global__ void k_scan3(int* __restrict__ rowptr, const int* __restrict__ bsum,
                        int n, int E) {
    int gid = blockIdx.x * 256 + threadIdx.x;
    if (gid < n) rowptr[gid] += bsum[blockIdx.x];
    if (gid == 0) rowptr[n] = E;
}

__global__ void k_dinv_i(const int* __restrict__ cnt, float* __restrict__ dinv, int n) {
    int i = blockIdx.x * blockDim.x + threadIdx.x;
    if (i < n) {
        int d = cnt[i];
        dinv[i] = d > 0 ? 1.0f / sqrtf((float)d) : 0.f;
    }
}

__global__ void k_scatter_all(Desc5 d, const int* __restrict__ rowptr,
                              int* __restrict__ cursor, int* __restrict__ colsp,
                              float* __restrict__ valsp, int Etot) {
    int e = blockIdx.x * blockDim.x + threadIdx.x;
    if (e >= Etot) return;
    int s = 0;
    while (e >= d.eoff[s + 1]) ++s;
    int le = e - d.eoff[s];
    int gr = d.doff[s] + d.rows[s][le];
    int pos = rowptr[gr] + atomicAdd(&cursor[gr], 1);
    colsp[pos] = d.cols[s][le];
    if (d.vals[s]) valsp[pos] = d.vals[s][le];
}

// ---------- gather SpMV (Cheb prop), 2x-unrolled edge loop ----------

__global__ void k_sprop3(const int* __restrict__ rowptr, const int* __restrict__ colsp,
                         const float* __restrict__ dinv, const float* __restrict__ src,
                         const float* __restrict__ prev, float* __restrict__ dst,
                         int n, int mode) {
    int r = blockIdx.x * blockDim.x + threadIdx.x;
    if (r >= n) return;
    int s0 = rowptr[r], s1 = rowptr[r + 1];
    float a0 = 0.f, a1 = 0.f, a2 = 0.f;
    float b0 = 0.f, b1 = 0.f, b2 = 0.f;
    int j = s0;
    for (; j + 2 <= s1; j += 2) {
        int ca = colsp[j], cb = colsp[j + 1];
        float wa = dinv[ca], wb = dinv[cb];
        const float* pa = src + (long long)ca * 3;
        const float* pb = src + (long long)cb * 3;
        a0 += wa * pa[0]; a1 += wa * pa[1]; a2 += wa * pa[2];
        b0 += wb * pb[0]; b1 += wb * pb[1]; b2 += wb * pb[2];
    }
    if (j < s1) {
        int c = colsp[j];
        float w = dinv[c];
        const float* sp = src + (long long)c * 3;
        a0 += w * sp[0]; a1 += w * sp[1]; a2 += w * sp[2];
    }
    a0 += b0; a1 += b1; a2 += b2;
    float m = -dinv[r];
    long long o = (long long)r * 3;
    if (mode) {
        dst[o]     = 2.f * m * a0 - prev[o];
        dst[o + 1] = 2.f * m * a1 - prev[o + 1];
        dst[o + 2] = 2.f * m * a2 - prev[o + 2];
    } else {
        dst[o] = m * a0; dst[o + 1] = m * a1; dst[o + 2] = m * a2;
    }
}

template <int C>
__global__ void k_sprop4_t(const int* __restrict__ rowptr, const int* __restrict__ colsp,
                           const float* __restrict__ dinv, const float* __restrict__ src,
                           const float* __restrict__ prev, float* __restrict__ dst,
                           int n, int mode) {
    constexpr int C4 = C / 4;
    int idx = blockIdx.x * blockDim.x + threadIdx.x;
    if (idx >= n * C4) return;
    int r = idx / C4, c4 = (idx - r * C4) * 4;
    int s0 = rowptr[r], s1 = rowptr[r + 1];
    float4 acca = make_float4(0.f, 0.f, 0.f, 0.f);
    float4 accb = make_float4(0.f, 0.f, 0.f, 0.f);
    int j = s0;
    for (; j + 2 <= s1; j += 2) {
        int ca = colsp[j], cb = colsp[j + 1];
        float wa = dinv[ca], wb = dinv[cb];
        float4 sa = *(const float4*)(src + (long long)ca * C + c4);
        float4 sb = *(const float4*)(src + (long long)cb * C + c4);
        acca.x += wa * sa.x; acca.y += wa * sa.y; acca.z += wa * sa.z; acca.w += wa * sa.w;
        accb.x += wb * sb.x; accb.y += wb * sb.y; accb.z += wb * sb.z; accb.w += wb * sb.w;
    }
    if (j < s1) {
        int c = colsp[j];
        float w = dinv[c];
        float4 s = *(const float4*)(src + (long long)c * C + c4);
        acca.x += w * s.x; acca.y += w * s.y; acca.z += w * s.z; acca.w += w * s.w;
    }
    acca.x += accb.x; acca.y += accb.y; acca.z += accb.z; acca.w += accb.w;
    float m = -dinv[r];
    long long o = (long long)r * C + c4;
    float4 out;
    if (mode) {
        float4 p = *(const float4*)(prev + o);
        out.x = 2.f * m * acca.x - p.x; out.y = 2.f * m * acca.y - p.y;
        out.z = 2.f * m * acca.z - p.z; out.w = 2.f * m * acca.w - p.w;
    } else {
        out.x = m * acca.x; out.y = m * acca.y; out.z = m * acca.z; out.w = m * acca.w;
    }
    *(float4*)(dst + o) = out;
}

// ---------- gather pool: out[r] = sum_j vals_j * relu(x[col_j]) ----------

template <int C>
__global__ void k_spool4_t(const int* __restrict__ rowptr, const int* __restrict__ colsp,
                           const float* __restrict__ valsp, const float* __restrict__ x,
                           float* __restrict__ out, int n) {
    constexpr int C4 = C / 4;
    int idx = blockIdx.x * blockDim.x + threadIdx.x;
    if (idx >= n * C4) return;
    int r = idx / C4, c4 = (idx - r * C4) * 4;
    int s0 = rowptr[r], s1 = rowptr[r + 1];
    float4 acca = make_float4(0.f, 0.f, 0.f, 0.f);
    float4 accb = make_float4(0.f, 0.f, 0.f, 0.f);
    int j = s0;
    for (; j + 2 <= s1; j += 2) {
        int ca = colsp[j], cb = colsp[j + 1];
        float va = valsp[j], vb = valsp[j + 1];
        float4 sa = *(const float4*)(x + (long long)ca * C + c4);
        float4 sb = *(const float4*)(x + (long long)cb * C + c4);
        acca.x += va * fmaxf(sa.x, 0.f); acca.y += va * fmaxf(sa.y, 0.f);
        acca.z += va * fmaxf(sa.z, 0.f); acca.w += va * fmaxf(sa.w, 0.f);
        accb.x += vb * fmaxf(sb.x, 0.f); accb.y += vb * fmaxf(sb.y, 0.f);
        accb.z += vb * fmaxf(sb.z, 0.f); accb.w += vb * fmaxf(sb.w, 0.f);
    }
    if (j < s1) {
        int c = colsp[j];
        float v = valsp[j];
        float4 s = *(const float4*)(x + (long long)c * C + c4);
        acca.x += v * fmaxf(s.x, 0.f); acca.y += v * fmaxf(s.y, 0.f);
        acca.z += v * fmaxf(s.z, 0.f); acca.w += v * fmaxf(s.w, 0.f);
    }
    acca.x += accb.x; acca.y += accb.y; acca.z += accb.z; acca.w += accb.w;
    *(float4*)(out + (long long)r * C + c4) = acca;
}

// ---------- fused output GEMM: out = b + sum_k Tx_k @ W[k] ----------
// Templated: full unroll, x-row staged in registers -> hundreds of
// independent loads in flight (was: runtime loop, 1 serial load wait/iter).

template <int CIN, int COUT>
__global__ void k_outgemm_t(float* __restrict__ out, TxPtrs txs,
                            const float* __restrict__ W, const float* __restrict__ b,
                            int n) {
    constexpr int CO4 = COUT / 4;
    int idx = blockIdx.x * blockDim.x + threadIdx.x;
    if (idx >= n * CO4) return;
    int node = idx / CO4, co = (idx - node * CO4) * 4;
    float4 acc = *(const float4*)(b + co);
#pragma unroll
    for (int k = 0; k < 6; ++k) {
        const float* xr = txs.p[k] + (long long)node * CIN;
        const float* Wk = W + k * CIN * COUT + co;
        if constexpr ((CIN & 3) == 0) {
            float4 xv[CIN / 4];
#pragma unroll
            for (int i = 0; i < CIN / 4; ++i) xv[i] = ((const float4*)xr)[i];
#pragma unroll
            for (int ci = 0; ci < CIN; ++ci) {
                float x = ((const float*)xv)[ci];
                float4 wv = *(const float4*)(Wk + ci * COUT);
                acc.x += x * wv.x; acc.y += x * wv.y;
                acc.z += x * wv.z; acc.w += x * wv.w;
            }
        } else {
            float xv[CIN];
#pragma unroll
            for (int i = 0; i < CIN; ++i) xv[i] = xr[i];
#pragma unroll
            for (int ci = 0; ci < CIN; ++ci) {
                float4 wv = *(const float4*)(Wk + ci * COUT);
                acc.x += xv[ci] * wv.x; acc.y += xv[ci] * wv.y;
                acc.z += xv[ci] * wv.z; acc.w += xv[ci] * wv.w;
            }
        }
    }
    *(float4*)(out + (long long)node * COUT + co) = acc;
}

// ---------- linear head, two-stage ----------

__global__ void k_linear_partial(const float* __restrict__ lw, const float* __restrict__ x,
                                 float* __restrict__ partials, int len4, int len, int nblk) {
    float acc[10];
#pragma unroll
    for (int j = 0; j < 10; ++j) acc[j] = 0.f;
    const float4* x4 = (const float4*)x;
    for (int i = blockIdx.x * blockDim.x + threadIdx.x; i < len4;
         i += gridDim.x * blockDim.x) {
        float4 xv = x4[i];
#pragma unroll
        for (int j = 0; j < 10; ++j) {
            float4 wv = *(const float4*)(lw + (long long)j * len + i * 4);
            acc[j] += xv.x * wv.x + xv.y * wv.y + xv.z * wv.z + xv.w * wv.w;
        }
    }
    __shared__ float lds[4][10];
    int wid = threadIdx.x >> 6, lane = threadIdx.x & 63;
#pragma unroll
    for (int j = 0; j < 10; ++j) {
        float v = acc[j];
        for (int off = 32; off > 0; off >>= 1) v += __shfl_down(v, off, 64);
        if (lane == 0) lds[wid][j] = v;
    }
    __syncthreads();
    if (threadIdx.x < 10) {
        float s = lds[0][threadIdx.x] + lds[1][threadIdx.x] +
                  lds[2][threadIdx.x] + lds[3][threadIdx.x];
        partials[threadIdx.x * nblk + blockIdx.x] = s;
    }
}

__global__ void k_linear_final(const float* __restrict__ partials,
                               const float* __restrict__ lb,
                               float* __restrict__ out, int nblk) {
    int j = threadIdx.x >> 6, lane = threadIdx.x & 63;
    float v = 0.f;
    for (int b = lane; b < nblk; b += 64) v += partials[j * nblk + b];
    for (int off = 32; off > 0; off >>= 1) v += __shfl_down(v, off, 64);
    if (lane == 0) out[j] = lb[j] + v;
}

extern "C" void kernel_launch(void* const* d_in, const int* in_sizes, int n_in,
                              void* d_out, int out_size, void* d_ws, size_t ws_size,
                              hipStream_t stream) {
    const int cN0 = 100000, cN1 = 25000, cN2 = 6250;
    const int cE0 = 600000, cE1 = 150000, cE2 = 40000;
    const int NBLK = 512;

    const float* pos = (const float*)d_in[0];
    const int*   ei0 = (const int*)d_in[1];
    const int*   ei1 = (const int*)d_in[2];
    const int*   ei2 = (const int*)d_in[3];
    const int*   d0r = (const int*)d_in[4];
    const int*   d0c = (const int*)d_in[5];
    const float* d0v = (const float*)d_in[6];
    const int*   d1r = (const int*)d_in[7];
    const int*   d1c = (const int*)d_in[8];
    const float* d1v = (const float*)d_in[9];
    const float* W0  = (const float*)d_in[10];
    const float* b0  = (const float*)d_in[11];
    const float* W1  = (const float*)d_in[12];
    const float* b1  = (const float*)d_in[13];
    const float* W2  = (const float*)d_in[14];
    const float* b2  = (const float*)d_in[15];
    const float* lw  = (const float*)d_in[16];
    const float* lb  = (const float*)d_in[17];
    float* outZ = (float*)d_out;

    // concatenated row space: g0 g1 g2 p0 p1
    const int ntot = cN0 + cN1 + cN2 + cN1 + cN2;          // 162500
    const int Etot = cE0 + cE1 + cE2 + cN0 + cN1;          // 915000
    const int doff0 = 0, doff1 = cN0, doff2 = cN0 + cN1,
              doffp0 = doff2 + cN2, doffp1 = doffp0 + cN1;

    // workspace layout (4B units)
    int*   iws    = (int*)d_ws;
    int*   ideg   = iws;                     // 162500
    int*   cursor = ideg + 162500;           // 162500 (adjacent: one memset)
    int*   rowptr = cursor + 162500;         // 162501
    int*   bsum   = rowptr + 162504;         // 704
    float* dinv   = (float*)(bsum + 704);    // 131250
    int*   colsp  = (int*)(dinv + 131250);   // 915000
    float* valsp  = (float*)(colsp + 915000);// 915000
    float* txbuf  = valsp + 915002;          // 5 x 800000 (16B aligned)
    float* bufOut = txbuf + 5 * 800000;      // 3200000
    float* bufPool= bufOut + 3200000;        // 800000
    float* lpart  = bufPool + 800000;        // 5120

    // ---- batched CSR build ----
    Desc5 d;
    d.rows[0] = ei0;        d.cols[0] = ei0 + cE0; d.vals[0] = nullptr;
    d.rows[1] = ei1;        d.cols[1] = ei1 + cE1; d.vals[1] = nullptr;
    d.rows[2] = ei2;        d.cols[2] = ei2 + cE2; d.vals[2] = nullptr;
    d.rows[3] = d0r;        d.cols[3] = d0c;       d.vals[3] = d0v;
    d.rows[4] = d1r;        d.cols[4] = d1c;       d.vals[4] = d1v;
    d.eoff[0] = 0;
    d.eoff[1] = cE0;
    d.eoff[2] = cE0 + cE1;
    d.eoff[3] = cE0 + cE1 + cE2;
    d.eoff[4] = cE0 + cE1 + cE2 + cN0;
    d.eoff[5] = Etot;
    d.doff[0] = doff0; d.doff[1] = doff1; d.doff[2] = doff2;
    d.doff[3] = doffp0; d.doff[4] = doffp1;

    hipMemsetAsync(ideg, 0, (size_t)(162500 + 162500) * 4, stream);
    k_count_all<<<gs(Etot), TPB, 0, stream>>>(d, ideg, Etot);
    int nb = (ntot + 255) / 256;
    k_scan1<<<nb, 256, 0, stream>>>(ideg, rowptr, bsum, ntot);
    k_scan2<<<1, 64, 0, stream>>>(bsum, nb);
    k_scan3<<<nb, 256, 0, stream>>>(rowptr, bsum, ntot, Etot);
    k_dinv_i<<<gs(cN0 + cN1 + cN2), TPB, 0, stream>>>(ideg, dinv, cN0 + cN1 + cN2);
    k_scatter_all<<<gs(Etot), TPB, 0, stream>>>(d, rowptr, cursor, colsp, valsp, Etot);

    auto conv = [&](const float* x, int doffs, int n, int Cin, int Cout,
                    const float* W, const float* b, float* out) {
        const int* rp = rowptr + doffs;
        const float* dv = dinv + doffs;
        auto sprop = [&](const float* src, const float* prev, float* dst, int mode) {
            if (Cin == 3)
                k_sprop3<<<gs(n), TPB, 0, stream>>>(rp, colsp, dv, src, prev, dst, n, mode);
            else if (Cin == 32)
                k_sprop4_t<32><<<gs((long long)n * 8), TPB, 0, stream>>>(
                    rp, colsp, dv, src, prev, dst, n, mode);
            else
                k_sprop4_t<64><<<gs((long long)n * 16), TPB, 0, stream>>>(
                    rp, colsp, dv, src, prev, dst, n, mode);
        };
        TxPtrs txs;
        txs.p[0] = x;
        for (int i = 1; i < 6; ++i) txs.p[i] = txbuf + (long long)(i - 1) * 800000;
        sprop(txs.p[0], nullptr, (float*)txs.p[1], 0);
        for (int k = 2; k < 6; ++k)
            sprop(txs.p[k - 1], txs.p[k - 2], (float*)txs.p[k], 1);
        if (Cin == 3)
            k_outgemm_t<3, 32><<<gs((long long)n * 8), TPB, 0, stream>>>(out, txs, W, b, n);
        else if (Cin == 32)
            k_outgemm_t<32, 64><<<gs((long long)n * 16), TPB, 0, stream>>>(out, txs, W, b, n);
        else
            k_outgemm_t<64, 128><<<gs((long long)n * 32), TPB, 0, stream>>>(out, txs, W, b, n);
    };

    // layer 0: pos (N0x3) -> bufOut (N0x32); pool -> bufPool (N1x32)
    conv(pos, doff0, cN0, 3, 32, W0, b0, bufOut);
    k_spool4_t<32><<<gs((long long)cN1 * 8), TPB, 0, stream>>>(
        rowptr + doffp0, colsp, valsp, bufOut, bufPool, cN1);

    // layer 1: bufPool (N1x32) -> bufOut (N1x64); pool -> bufPool (N2x64)
    conv(bufPool, doff1, cN1, 32, 64, W1, b1, bufOut);
    k_spool4_t<64><<<gs((long long)cN2 * 16), TPB, 0, stream>>>(
        rowptr + doffp1, colsp, valsp, bufOut, bufPool, cN2);

    // layer 2: bufPool (N2x64) -> bufOut (N2x128), no relu
    conv(bufPool, doff2, cN2, 64, 128, W2, b2, bufOut);

    // linear head
    k_linear_partial<<<NBLK, TPB, 0, stream>>>(lw, bufOut, lpart, cN2 * 128 / 4, cN2 * 128, NBLK);
    k_linear_final<<<1, 640, 0, stream>>>(lpart, lb, outZ, NBLK);
}

// Round 6
// 366.616 us; speedup vs baseline: 3.7399x; 1.0030x over previous
//
#include <hip/hip_runtime.h>

// ChebNet classifier: 3x ChebConv(K=6) + 2x sparse pool + linear head.
// R5: layer-2 outgemm was latency-bound (200k threads, 480 loads/thread,
//     VALU 7%). (a) k-split out-GEMMs across grid (6x threads, 1/6 chain),
//     partial-reduce FUSED into consumers (pool1 gather / linear head);
//     (b) precomputed wcol[e]=dinv[col[e]] kills 2-level indirection in
//     sprop; (c) layer-0 stride-4 padding (float4 rows, no scalar loads).

#define TPB 256

static inline int gs(long long n) { return (int)((n + TPB - 1) / TPB); }

struct Desc5 {
    const int* rows[5];
    const int* cols[5];
    const float* vals[5];
    int eoff[6];
    int doff[5];
};

struct TxPtrs { const float* p[6]; };

// ---------- batched CSR build ----------

__global__ void k_count_all(Desc5 d, int* __restrict__ cnt, int Etot) {
    int e = blockIdx.x * blockDim.x + threadIdx.x;
    if (e >= Etot) return;
    int s = 0;
    while (e >= d.eoff[s + 1]) ++s;
    int le = e - d.eoff[s];
    atomicAdd(&cnt[d.doff[s] + d.rows[s][le]], 1);
}

__global__ void k_scan1(const int* __restrict__ cnt, int* __restrict__ excl,
                        int* __restrict__ bsum, int n) {
    int gid = blockIdx.x * 256 + threadIdx.x;
    int v = (gid < n) ? cnt[gid] : 0;
    int lane = threadIdx.x & 63, wid = threadIdx.x >> 6;
    int s = v;
#pragma unroll
    for (int off = 1; off < 64; off <<= 1) {
        int t = __shfl_up(s, off, 64);
        if (lane >= off) s += t;
    }
    __shared__ int wsum[4];
    if (lane == 63) wsum[wid] = s;
    __syncthreads();
    int add = 0;
    for (int w = 0; w < wid; ++w) add += wsum[w];
    if (gid < n) excl[gid] = add + s - v;
    if (threadIdx.x == 255) bsum[blockIdx.x] = add + s;
}

__global__ void k_scan2(int* __restrict__ bsum, int nb) {
    int lane = threadIdx.x;  // blockDim = 64
    int carry = 0;
    for (int base = 0; base < nb; base += 64) {
        int i = base + lane;
        int v = (i < nb) ? bsum[i] : 0;
        int s = v;
#pragma unroll
        for (int off = 1; off < 64; off <<= 1) {
            int t = __shfl_up(s, off, 64);
            if (lane >= off) s += t;
        }
        if (i < nb) bsum[i] = carry + s - v;
        carry += __shfl(s, 63, 64);
    }
}

__global__ void k_scan3(int* __restrict__ rowptr, const int* __restrict__ bsum,
                        int n, int E) {
    int gid = blockIdx.x * 256 + threadIdx.x;
    if (gid < n) rowptr[gid] += bsum[blockIdx.x];
    if (gid == 0) rowptr[n] = E;
}

__global__ void k_dinv_i(const int* __restrict__ cnt, float* __restrict__ dinv, int n) {
    int i = blockIdx.x * blockDim.x + threadIdx.x;
    if (i < n) {
        int d = cnt[i];
        dinv[i] = d > 0 ? 1.0f / sqrtf((float)d) : 0.f;
    }
}

__global__ void k_scatter_all(Desc5 d, const int* __restrict__ rowptr,
                              int* __restrict__ cursor, int* __restrict__ colsp,
                              float* __restrict__ valsp, int Etot) {
    int e = blockIdx.x * blockDim.x + threadIdx.x;
    if (e >= Etot) return;
    int s = 0;
    while (e >= d.eoff[s + 1]) ++s;
    int le = e - d.eoff[s];
    int gr = d.doff[s] + d.rows[s][le];
    int pos = rowptr[gr] + atomicAdd(&cursor[gr], 1);
    colsp[pos] = d.cols[s][le];
    if (d.vals[s]) valsp[pos] = d.vals[s][le];
}

// wcol[e] = dinv[segment_base + colsp[e]] for the 3 graph segments
__global__ void k_wcol(const int* __restrict__ colsp, const float* __restrict__ dinv,
                       float* __restrict__ wcol, int Eg) {
    int e = blockIdx.x * blockDim.x + threadIdx.x;
    if (e >= Eg) return;
    int base = (e < 600000) ? 0 : (e < 750000 ? 100000 : 125000);
    wcol[e] = dinv[base + colsp[e]];
}

// pos (N0 x 3) -> pos4 (N0 x 4, w = 0)
__global__ void k_pad4(const float* __restrict__ pos, float4* __restrict__ pos4, int n) {
    int i = blockIdx.x * blockDim.x + threadIdx.x;
    if (i < n) pos4[i] = make_float4(pos[3 * i], pos[3 * i + 1], pos[3 * i + 2], 0.f);
}

// ---------- gather SpMV (Cheb prop): linear colsp+wcol, 1-level indirection ----------
// acc = sum_j wcol_j * src[col_j]; prop = -dinv[r]*acc
// mode 0: dst = prop ; mode 1: dst = 2*prop - prev

template <int C>
__global__ void k_sprop_t(const int* __restrict__ rowptr, const int* __restrict__ colsp,
                          const float* __restrict__ wcol, const float* __restrict__ dinv,
                          const float* __restrict__ src, const float* __restrict__ prev,
                          float* __restrict__ dst, int n, int mode) {
    constexpr int C4 = C / 4;
    int idx = blockIdx.x * blockDim.x + threadIdx.x;
    if (idx >= n * C4) return;
    int r = idx / C4, c4 = (idx - r * C4) * 4;
    int s0 = rowptr[r], s1 = rowptr[r + 1];
    float4 acca = make_float4(0.f, 0.f, 0.f, 0.f);
    float4 accb = make_float4(0.f, 0.f, 0.f, 0.f);
    int j = s0;
    for (; j + 2 <= s1; j += 2) {
        int ca = colsp[j], cb = colsp[j + 1];
        float wa = wcol[j], wb = wcol[j + 1];
        float4 sa = *(const float4*)(src + (long long)ca * C + c4);
        float4 sb = *(const float4*)(src + (long long)cb * C + c4);
        acca.x += wa * sa.x; acca.y += wa * sa.y; acca.z += wa * sa.z; acca.w += wa * sa.w;
        accb.x += wb * sb.x; accb.y += wb * sb.y; accb.z += wb * sb.z; accb.w += wb * sb.w;
    }
    if (j < s1) {
        int c = colsp[j];
        float w = wcol[j];
        float4 s = *(const float4*)(src + (long long)c * C + c4);
        acca.x += w * s.x; acca.y += w * s.y; acca.z += w * s.z; acca.w += w * s.w;
    }
    acca.x += accb.x; acca.y += accb.y; acca.z += accb.z; acca.w += accb.w;
    float m = -dinv[r];
    long long o = (long long)r * C + c4;
    float4 out;
    if (mode) {
        float4 p = *(const float4*)(prev + o);
        out.x = 2.f * m * acca.x - p.x; out.y = 2.f * m * acca.y - p.y;
        out.z = 2.f * m * acca.z - p.z; out.w = 2.f * m * acca.w - p.w;
    } else {
        out.x = m * acca.x; out.y = m * acca.y; out.z = m * acca.z; out.w = m * acca.w;
    }
    *(float4*)(dst + o) = out;
}

// ---------- pool0: out[r] = sum_j vals_j * relu(x[col_j]) ----------

template <int C>
__global__ void k_spool4_t(const int* __restrict__ rowptr, const int* __restrict__ colsp,
                           const float* __restrict__ valsp, const float* __restrict__ x,
                           float* __restrict__ out, int n) {
    constexpr int C4 = C / 4;
    int idx = blockIdx.x * blockDim.x + threadIdx.x;
    if (idx >= n * C4) return;
    int r = idx / C4, c4 = (idx - r * C4) * 4;
    int s0 = rowptr[r], s1 = rowptr[r + 1];
    float4 acca = make_float4(0.f, 0.f, 0.f, 0.f);
    float4 accb = make_float4(0.f, 0.f, 0.f, 0.f);
    int j = s0;
    for (; j + 2 <= s1; j += 2) {
        int ca = colsp[j], cb = colsp[j + 1];
        float va = valsp[j], vb = valsp[j + 1];
        float4 sa = *(const float4*)(x + (long long)ca * C + c4);
        float4 sb = *(const float4*)(x + (long long)cb * C + c4);
        acca.x += va * fmaxf(sa.x, 0.f); acca.y += va * fmaxf(sa.y, 0.f);
        acca.z += va * fmaxf(sa.z, 0.f); acca.w += va * fmaxf(sa.w, 0.f);
        accb.x += vb * fmaxf(sb.x, 0.f); accb.y += vb * fmaxf(sb.y, 0.f);
        accb.z += vb * fmaxf(sb.z, 0.f); accb.w += vb * fmaxf(sb.w, 0.f);
    }
    if (j < s1) {
        int c = colsp[j];
        float v = valsp[j];
        float4 s = *(const float4*)(x + (long long)c * C + c4);
        acca.x += v * fmaxf(s.x, 0.f); acca.y += v * fmaxf(s.y, 0.f);
        acca.z += v * fmaxf(s.z, 0.f); acca.w += v * fmaxf(s.w, 0.f);
    }
    acca.x += accb.x; acca.y += accb.y; acca.z += accb.z; acca.w += accb.w;
    *(float4*)(out + (long long)r * C + c4) = acca;
}

// ---------- pool1 fused with layer-1 partial reduce + bias + relu ----------
// out[r][c..] = sum_j val_j * relu(b[c..] + sum_s part_s[col_j][c..])

template <int C, int KSPLIT>
__global__ void k_pool_f(const int* __restrict__ rowptr, const int* __restrict__ colsp,
                         const float* __restrict__ valsp, const float* __restrict__ part,
                         const float* __restrict__ bias, float* __restrict__ out,
                         int n, int partStride) {
    constexpr int C4 = C / 4;
    int idx = blockIdx.x * blockDim.x + threadIdx.x;
    if (idx >= n * C4) return;
    int r = idx / C4, c4 = (idx - r * C4) * 4;
    int s0 = rowptr[r], s1 = rowptr[r + 1];
    float4 bb = *(const float4*)(bias + c4);
    float4 acc = make_float4(0.f, 0.f, 0.f, 0.f);
    for (int j = s0; j < s1; ++j) {
        int c = colsp[j];
        float v = valsp[j];
        float4 x = bb;
#pragma unroll
        for (int s = 0; s < KSPLIT; ++s) {
            float4 p = *(const float4*)(part + (long long)s * partStride + (long long)c * C + c4);
            x.x += p.x; x.y += p.y; x.z += p.z; x.w += p.w;
        }
        acc.x += v * fmaxf(x.x, 0.f); acc.y += v * fmaxf(x.y, 0.f);
        acc.z += v * fmaxf(x.z, 0.f); acc.w += v * fmaxf(x.w, 0.f);
    }
    *(float4*)(out + (long long)r * C + c4) = acc;
}

// ---------- layer-0 direct out-GEMM (CIN=3 stride 4, COUT=32) ----------

__global__ void k_outgemm0(float* __restrict__ out, TxPtrs txs,
                           const float* __restrict__ W, const float* __restrict__ b,
                           int n) {
    int idx = blockIdx.x * blockDim.x + threadIdx.x;
    if (idx >= n * 8) return;
    int node = idx >> 3, co = (idx & 7) * 4;
    float4 acc = *(const float4*)(b + co);
#pragma unroll
    for (int k = 0; k < 6; ++k) {
        float4 xv = ((const float4*)txs.p[k])[node];
        const float* Wk = W + k * 96 + co;
        float4 w0 = *(const float4*)(Wk);
        float4 w1 = *(const float4*)(Wk + 32);
        float4 w2 = *(const float4*)(Wk + 64);
        acc.x += xv.x * w0.x + xv.y * w1.x + xv.z * w2.x;
        acc.y += xv.x * w0.y + xv.y * w1.y + xv.z * w2.y;
        acc.z += xv.x * w0.z + xv.y * w1.z + xv.z * w2.z;
        acc.w += xv.x * w0.w + xv.y * w1.w + xv.z * w2.w;
    }
    *(float4*)(out + (long long)node * 32 + co) = acc;
}

// ---------- k-split out-GEMM: part_s = sum_{k in split s} Tx_k @ W[k] ----------

template <int CIN, int COUT, int KSPLIT>
__global__ void k_outsplit_t(float* __restrict__ part, TxPtrs txs,
                             const float* __restrict__ W, int n, int partStride) {
    constexpr int CO4 = COUT / 4;
    constexpr int KPER = 6 / KSPLIT;
    int idx = blockIdx.x * blockDim.x + threadIdx.x;
    int per = n * CO4;
    if (idx >= per * KSPLIT) return;
    int s = idx / per, t = idx - s * per;
    int node = t / CO4, co = (t - node * CO4) * 4;
    float4 acc = make_float4(0.f, 0.f, 0.f, 0.f);
#pragma unroll
    for (int kk = 0; kk < KPER; ++kk) {
        int k = s * KPER + kk;
        const float* xr = txs.p[k] + (long long)node * CIN;
        float4 xv[CIN / 4];
#pragma unroll
        for (int i = 0; i < CIN / 4; ++i) xv[i] = ((const float4*)xr)[i];
        const float* Wk = W + (long long)k * CIN * COUT + co;
#pragma unroll
        for (int ci = 0; ci < CIN; ++ci) {
            float x = ((const float*)xv)[ci];
            float4 wv = *(const float4*)(Wk + ci * COUT);
            acc.x += x * wv.x; acc.y += x * wv.y;
            acc.z += x * wv.z; acc.w += x * wv.w;
        }
    }
    *(float4*)(part + (long long)s * partStride + (long long)node * COUT + co) = acc;
}

// ---------- linear head, fused with layer-2 partial reduce + bias ----------

__global__ void k_linear_partial_f(const float* __restrict__ lw,
                                   const float4* __restrict__ part,
                                   const float* __restrict__ b2,
                                   float* __restrict__ partials,
                                   int len4, int len, int nblk) {
    float acc[10];
#pragma unroll
    for (int j = 0; j < 10; ++j) acc[j] = 0.f;
    const float4* b2v = (const float4*)b2;
    for (int i = blockIdx.x * blockDim.x + threadIdx.x; i < len4;
         i += gridDim.x * blockDim.x) {
        float4 xv = b2v[i & 31];
#pragma unroll
        for (int s = 0; s < 6; ++s) {
            float4 p = part[s * 200000 + i];
            xv.x += p.x; xv.y += p.y; xv.z += p.z; xv.w += p.w;
        }
#pragma unroll
        for (int j = 0; j < 10; ++j) {
            float4 wv = *(const float4*)(lw + (long long)j * len + i * 4);
            acc[j] += xv.x * wv.x + xv.y * wv.y + xv.z * wv.z + xv.w * wv.w;
        }
    }
    __shared__ float lds[4][10];
    int wid = threadIdx.x >> 6, lane = threadIdx.x & 63;
#pragma unroll
    for (int j = 0; j < 10; ++j) {
        float v = acc[j];
        for (int off = 32; off > 0; off >>= 1) v += __shfl_down(v, off, 64);
        if (lane == 0) lds[wid][j] = v;
    }
    __syncthreads();
    if (threadIdx.x < 10) {
        float s = lds[0][threadIdx.x] + lds[1][threadIdx.x] +
                  lds[2][threadIdx.x] + lds[3][threadIdx.x];
        partials[threadIdx.x * nblk + blockIdx.x] = s;
    }
}

__global__ void k_linear_final(const float* __restrict__ partials,
                               const float* __restrict__ lb,
                               float* __restrict__ out, int nblk) {
    int j = threadIdx.x >> 6, lane = threadIdx.x & 63;
    float v = 0.f;
    for (int b = lane; b < nblk; b += 64) v += partials[j * nblk + b];
    for (int off = 32; off > 0; off >>= 1) v += __shfl_down(v, off, 64);
    if (lane == 0) out[j] = lb[j] + v;
}

extern "C" void kernel_launch(void* const* d_in, const int* in_sizes, int n_in,
                              void* d_out, int out_size, void* d_ws, size_t ws_size,
                              hipStream_t stream) {
    const int cN0 = 100000, cN1 = 25000, cN2 = 6250;
    const int cE0 = 600000, cE1 = 150000, cE2 = 40000;
    const int NBLK = 512;

    const float* pos = (const float*)d_in[0];
    const int*   ei0 = (const int*)d_in[1];
    const int*   ei1 = (const int*)d_in[2];
    const int*   ei2 = (const int*)d_in[3];
    const int*   d0r = (const int*)d_in[4];
    const int*   d0c = (const int*)d_in[5];
    const float* d0v = (const float*)d_in[6];
    const int*   d1r = (const int*)d_in[7];
    const int*   d1c = (const int*)d_in[8];
    const float* d1v = (const float*)d_in[9];
    const float* W0  = (const float*)d_in[10];
    const float* b0  = (const float*)d_in[11];
    const float* W1  = (const float*)d_in[12];
    const float* b1  = (const float*)d_in[13];
    const float* W2  = (const float*)d_in[14];
    const float* b2  = (const float*)d_in[15];
    const float* lw  = (const float*)d_in[16];
    const float* lb  = (const float*)d_in[17];
    float* outZ = (float*)d_out;

    // concatenated row space: g0 g1 g2 p0 p1
    const int ntot = cN0 + cN1 + cN2 + cN1 + cN2;          // 162500
    const int Etot = cE0 + cE1 + cE2 + cN0 + cN1;          // 915000
    const int Eg   = cE0 + cE1 + cE2;                      // 790000 (graph edges)
    const int doff0 = 0, doff1 = cN0, doff2 = cN0 + cN1,
              doffp0 = doff2 + cN2, doffp1 = doffp0 + cN1;

    // workspace layout (4B units); all float4 bases 16B-aligned
    int*   iws    = (int*)d_ws;
    int*   ideg   = iws;                         // 162500
    int*   cursor = ideg + 162500;               // 162500 (adjacent: one memset)
    int*   rowptr = cursor + 162500;             // 162504
    int*   bsum   = rowptr + 162504;             // 704
    float* dinv   = (float*)(bsum + 704);        // 131256
    int*   colsp  = (int*)(dinv + 131256);       // 915000
    float* valsp  = (float*)(colsp + 915000);    // 915000
    float* wcol   = valsp + 915000;              // 790000
    float* pos4   = wcol + 790000;               // 400000
    float* txbuf  = pos4 + 400000;               // 5 x 800000
    float* part   = txbuf + 5 * 800000;          // 4800000
    float* bufOut = part + 4800000;              // 3200000
    float* bufPool= bufOut + 3200000;            // 800000
    float* lpart  = bufPool + 800000;            // 5120

    // ---- independent prep ----
    k_pad4<<<gs(cN0), TPB, 0, stream>>>(pos, (float4*)pos4, cN0);

    // ---- batched CSR build ----
    Desc5 d;
    d.rows[0] = ei0;        d.cols[0] = ei0 + cE0; d.vals[0] = nullptr;
    d.rows[1] = ei1;        d.cols[1] = ei1 + cE1; d.vals[1] = nullptr;
    d.rows[2] = ei2;        d.cols[2] = ei2 + cE2; d.vals[2] = nullptr;
    d.rows[3] = d0r;        d.cols[3] = d0c;       d.vals[3] = d0v;
    d.rows[4] = d1r;        d.cols[4] = d1c;       d.vals[4] = d1v;
    d.eoff[0] = 0;
    d.eoff[1] = cE0;
    d.eoff[2] = cE0 + cE1;
    d.eoff[3] = Eg;
    d.eoff[4] = Eg + cN0;
    d.eoff[5] = Etot;
    d.doff[0] = doff0; d.doff[1] = doff1; d.doff[2] = doff2;
    d.doff[3] = doffp0; d.doff[4] = doffp1;

    hipMemsetAsync(ideg, 0, (size_t)(162500 + 162500) * 4, stream);
    k_count_all<<<gs(Etot), TPB, 0, stream>>>(d, ideg, Etot);
    int nb = (ntot + 255) / 256;
    k_scan1<<<nb, 256, 0, stream>>>(ideg, rowptr, bsum, ntot);
    k_scan2<<<1, 64, 0, stream>>>(bsum, nb);
    k_scan3<<<nb, 256, 0, stream>>>(rowptr, bsum, ntot, Etot);
    k_dinv_i<<<gs(cN0 + cN1 + cN2), TPB, 0, stream>>>(ideg, dinv, cN0 + cN1 + cN2);
    k_scatter_all<<<gs(Etot), TPB, 0, stream>>>(d, rowptr, cursor, colsp, valsp, Etot);
    k_wcol<<<gs(Eg), TPB, 0, stream>>>(colsp, dinv, wcol, Eg);

    // ---- generic Tx recurrence ----
    auto run_sprops = [&](const float* x, int doffs, int n, int Cs, TxPtrs& txs) {
        const int* rp = rowptr + doffs;
        const float* dv = dinv + doffs;
        auto sprop = [&](const float* src, const float* prev, float* dst, int mode) {
            long long work = (long long)n * (Cs >> 2);
            if (Cs == 4)
                k_sprop_t<4><<<gs(work), TPB, 0, stream>>>(rp, colsp, wcol, dv, src, prev, dst, n, mode);
            else if (Cs == 32)
                k_sprop_t<32><<<gs(work), TPB, 0, stream>>>(rp, colsp, wcol, dv, src, prev, dst, n, mode);
            else
                k_sprop_t<64><<<gs(work), TPB, 0, stream>>>(rp, colsp, wcol, dv, src, prev, dst, n, mode);
        };
        txs.p[0] = x;
        for (int i = 1; i < 6; ++i) txs.p[i] = txbuf + (long long)(i - 1) * 800000;
        sprop(txs.p[0], nullptr, (float*)txs.p[1], 0);
        for (int k = 2; k < 6; ++k)
            sprop(txs.p[k - 1], txs.p[k - 2], (float*)txs.p[k], 1);
    };

    // ---- layer 0: pos4 (N0x4, CIN=3) -> bufOut (N0x32); pool0 -> bufPool ----
    {
        TxPtrs txs;
        run_sprops(pos4, doff0, cN0, 4, txs);
        k_outgemm0<<<gs((long long)cN0 * 8), TPB, 0, stream>>>(bufOut, txs, W0, b0, cN0);
        k_spool4_t<32><<<gs((long long)cN1 * 8), TPB, 0, stream>>>(
            rowptr + doffp0, colsp, valsp, bufOut, bufPool, cN1);
    }

    // ---- layer 1: bufPool (N1x32) -> part[0..2] (each N1x64); pool1 fused ----
    {
        TxPtrs txs;
        run_sprops(bufPool, doff1, cN1, 32, txs);
        const int pstride = cN1 * 64;  // 1600000
        k_outsplit_t<32, 64, 3><<<gs((long long)cN1 * 16 * 3), TPB, 0, stream>>>(
            part, txs, W1, cN1, pstride);
        k_pool_f<64, 3><<<gs((long long)cN2 * 16), TPB, 0, stream>>>(
            rowptr + doffp1, colsp, valsp, part, b1, bufPool, cN2, pstride);
    }

    // ---- layer 2: bufPool (N2x64) -> part[0..5] (each N2x128); head fused ----
    {
        TxPtrs txs;
        run_sprops(bufPool, doff2, cN2, 64, txs);
        const int pstride = cN2 * 128;  // 800000
        k_outsplit_t<64, 128, 6><<<gs((long long)cN2 * 32 * 6), TPB, 0, stream>>>(
            part, txs, W2, cN2, pstride);
        k_linear_partial_f<<<NBLK, TPB, 0, stream>>>(
            lw, (const float4*)part, b2, lpart, cN2 * 128 / 4, cN2 * 128, NBLK);
        k_linear_final<<<1, 640, 0, stream>>>(lpart, lb, outZ, NBLK);
    }
}